// Round 9
// baseline (712.235 us; speedup 1.0000x reference)
//
#include <hip/hip_runtime.h>
#include <hip/hip_bf16.h>

#define DD 64
#define SCAN_CH 1024
#define MST 68   // fp32 LDS row stride: conflict-free

typedef __attribute__((ext_vector_type(8))) short bf16x8;
typedef __attribute__((ext_vector_type(4))) float f32x4;

__device__ __forceinline__ unsigned short f2bf(float f) {
    unsigned int u = __float_as_uint(f);
    unsigned int r = (u + 0x7fffu + ((u >> 16) & 1u)) >> 16;   // RNE
    return (unsigned short)r;
}
__device__ __forceinline__ float bf2f(unsigned short u) {
    return __uint_as_float((unsigned int)u << 16);
}
__device__ __forceinline__ unsigned int pack2(float lo, float hi) {
    return (unsigned int)f2bf(lo) | ((unsigned int)f2bf(hi) << 16);
}

// B frag for 16x16x32: lane l holds B[k = ks*32 + (l>>4)*8 + b][col = nt*16 + (l&15)]
__device__ __forceinline__ void load_w_frags(const float* __restrict__ W, int lane,
                                             bf16x8 bw[4][2]) {
    const int kl = (lane >> 4) * 8;
    const int cl = lane & 15;
#pragma unroll
    for (int nt = 0; nt < 4; ++nt)
#pragma unroll
        for (int ks = 0; ks < 2; ++ks)
#pragma unroll
            for (int b = 0; b < 8; ++b)
                bw[nt][ks][b] = (short)f2bf(W[(ks * 32 + kl + b) * DD + nt * 16 + cl]);
}

#define MFMA8(A0, A1)                                                          \
    acc0 = __builtin_amdgcn_mfma_f32_16x16x32_bf16(A0, bw[0][0], acc0, 0, 0, 0); \
    acc0 = __builtin_amdgcn_mfma_f32_16x16x32_bf16(A1, bw[0][1], acc0, 0, 0, 0); \
    acc1 = __builtin_amdgcn_mfma_f32_16x16x32_bf16(A0, bw[1][0], acc1, 0, 0, 0); \
    acc1 = __builtin_amdgcn_mfma_f32_16x16x32_bf16(A1, bw[1][1], acc1, 0, 0, 0); \
    acc2 = __builtin_amdgcn_mfma_f32_16x16x32_bf16(A0, bw[2][0], acc2, 0, 0, 0); \
    acc2 = __builtin_amdgcn_mfma_f32_16x16x32_bf16(A1, bw[2][1], acc2, 0, 0, 0); \
    acc3 = __builtin_amdgcn_mfma_f32_16x16x32_bf16(A0, bw[3][0], acc3, 0, 0, 0); \
    acc3 = __builtin_amdgcn_mfma_f32_16x16x32_bf16(A1, bw[3][1], acc3, 0, 0, 0);

// ---------- x-table prep ----------
__global__ __launch_bounds__(256) void xprep_kernel(
    const float4* __restrict__ feat4, const float4* __restrict__ emb4,
    const int* __restrict__ rel, unsigned short* __restrict__ xtab, int n4) {
    int i = blockIdx.x * blockDim.x + threadIdx.x;
    const int stride = gridDim.x * blockDim.x;
    for (; i < n4; i += stride) {
        const int e  = i >> 4;
        const int re = rel[e];
        const float4 f = feat4[i];
        const float4 g = emb4[re * 16 + (i & 15)];
        ushort4 o;
        o.x = f2bf(f.x + g.x); o.y = f2bf(f.y + g.y);
        o.z = f2bf(f.z + g.z); o.w = f2bf(f.w + g.w);
        *reinterpret_cast<ushort4*>(&xtab[(size_t)i * 4]) = o;
    }
}

// ---------- binning: bin = ac >> 4 (16 edges/bin, L2-resident tables) ----------
__global__ __launch_bounds__(256) void hist_bin_kernel(const int* __restrict__ ac,
                                                       unsigned int* __restrict__ cnt, int T_) {
    int t = blockIdx.x * blockDim.x + threadIdx.x;
    const int stride = gridDim.x * blockDim.x;
    for (; t < T_; t += stride) atomicAdd(&cnt[ac[t] >> 4], 1u);
}

__global__ __launch_bounds__(256) void scanA_kernel(const unsigned int* __restrict__ cnt,
                                                    unsigned int* __restrict__ bsum, int n) {
    __shared__ unsigned int s[256];
    const int b = blockIdx.x, tid = threadIdx.x;
    const int base = b * SCAN_CH + tid * 4;
    unsigned int v = 0;
#pragma unroll
    for (int k = 0; k < 4; ++k) { const int i = base + k; if (i < n) v += cnt[i]; }
    s[tid] = v; __syncthreads();
    for (int off = 128; off > 0; off >>= 1) {
        if (tid < off) s[tid] += s[tid + off];
        __syncthreads();
    }
    if (tid == 0) bsum[b] = s[0];
}

__global__ __launch_bounds__(1024) void scanB_kernel(unsigned int* bsum, int nb) {
    __shared__ unsigned int s[1024];
    const int tid = threadIdx.x;
    s[tid] = (tid < nb) ? bsum[tid] : 0u;
    __syncthreads();
    for (int off = 1; off < 1024; off <<= 1) {
        const unsigned int t = (tid >= off) ? s[tid - off] : 0u;
        __syncthreads();
        s[tid] += t;
        __syncthreads();
    }
    if (tid < nb) bsum[tid] = (tid == 0) ? 0u : s[tid - 1];   // exclusive
}

__global__ __launch_bounds__(256) void scanC_kernel(const unsigned int* __restrict__ cnt,
                                                    const unsigned int* __restrict__ bsum,
                                                    unsigned int* __restrict__ offs, int n) {
    __shared__ unsigned int s[256];
    const int b = blockIdx.x, tid = threadIdx.x;
    const int base = b * SCAN_CH + tid * 4;
    unsigned int v[4], sum = 0;
#pragma unroll
    for (int k = 0; k < 4; ++k) { const int i = base + k; v[k] = (i < n) ? cnt[i] : 0u; sum += v[k]; }
    s[tid] = sum; __syncthreads();
    for (int off = 1; off < 256; off <<= 1) {
        const unsigned int t = (tid >= off) ? s[tid - off] : 0u;
        __syncthreads();
        s[tid] += t;
        __syncthreads();
    }
    unsigned int run = bsum[b] + (s[tid] - sum);
#pragma unroll
    for (int k = 0; k < 4; ++k) { const int i = base + k; if (i < n) offs[i] = run; run += v[k]; }
}

// tep[pos] = {ab,bc,ac,0}; bin regions are 512B -> dense, write-combining works
__global__ __launch_bounds__(256) void scatter_pre_kernel(
    const int* __restrict__ ab, const int* __restrict__ bc, const int* __restrict__ ac,
    unsigned int* __restrict__ offs, uint4* __restrict__ tep, int T_) {
    int t = blockIdx.x * blockDim.x + threadIdx.x;
    const int stride = gridDim.x * blockDim.x;
    for (; t < T_; t += stride) {
        const int e = ac[t];
        const unsigned int pos = atomicAdd(&offs[e >> 4], 1u);
        tep[pos] = make_uint4((unsigned)ab[t], (unsigned)bc[t], (unsigned)e, 0u);
    }
}

// ---------- binned message+reduce: one bin (16 edges) per wave, zero atomics ----------
__global__ __launch_bounds__(256) void tri_bin_kernel(
    const unsigned short* __restrict__ xtab, const float* __restrict__ Wmsg,
    const uint4* __restrict__ tep, const unsigned int* __restrict__ cnt,
    const unsigned int* __restrict__ offs_end, unsigned short* __restrict__ aggbf,
    int E_, int NBINS) {
    __shared__ unsigned short P[4][16 * 64];
    __shared__ float M[4][16 * MST];
    __shared__ float A[4][16 * 64];   // fp32 bin accumulator (lane=col; 2-way bank = free)

    const int lane = threadIdx.x & 63;
    const int w    = threadIdx.x >> 6;

    bf16x8 bw[4][2];
    load_w_frags(Wmsg, lane, bw);

    const int wave   = (blockIdx.x * blockDim.x + threadIdx.x) >> 6;
    const int nwaves = (gridDim.x * blockDim.x) >> 6;

    const int side = (lane >> 3) & 1;
    const int cb   = (lane & 7) * 8;
    const int tsub = lane >> 4;

    for (int bin = wave; bin < NBINS; bin += nwaves) {
        const int n  = (int)cnt[bin];
        const int st = (int)offs_end[bin] - n;

        // zero the bin accumulator
#pragma unroll
        for (int r = 0; r < 16; ++r) A[w][r * 64 + lane] = 0.f;

        for (int t0 = 0; t0 < n; t0 += 16) {
            const int ctile = min(16, n - t0);
            const uint4 tq = tep[st + t0 + min(lane & 15, ctile - 1)];

            // ---- wide gathers + product -> swizzled LDS ----
#pragma unroll
            for (int ld = 0; ld < 4; ++ld) {
                const int ttl = ld * 4 + tsub;
                const int eA  = __shfl((int)tq.x, ttl, 64);
                const int eB  = __shfl((int)tq.y, ttl, 64);
                const int e   = side ? eB : eA;
                const uint4 v = *reinterpret_cast<const uint4*>(&xtab[(size_t)e * DD + cb]);
                uint4 o;
                o.x = (unsigned)__shfl_xor((int)v.x, 8, 64);
                o.y = (unsigned)__shfl_xor((int)v.y, 8, 64);
                o.z = (unsigned)__shfl_xor((int)v.z, 8, 64);
                o.w = (unsigned)__shfl_xor((int)v.w, 8, 64);
                if (!side) {
                    uint4 pk;
                    pk.x = pack2(bf2f(v.x & 0xffffu) * bf2f(o.x & 0xffffu),
                                 bf2f(v.x >> 16)     * bf2f(o.x >> 16));
                    pk.y = pack2(bf2f(v.y & 0xffffu) * bf2f(o.y & 0xffffu),
                                 bf2f(v.y >> 16)     * bf2f(o.y >> 16));
                    pk.z = pack2(bf2f(v.z & 0xffffu) * bf2f(o.z & 0xffffu),
                                 bf2f(v.z >> 16)     * bf2f(o.z >> 16));
                    pk.w = pack2(bf2f(v.w & 0xffffu) * bf2f(o.w & 0xffffu),
                                 bf2f(v.w >> 16)     * bf2f(o.w >> 16));
                    const int swz = (ttl & 7) << 3;
                    *reinterpret_cast<uint4*>(&P[w][ttl * 64 + (cb ^ swz)]) = pk;
                }
            }

            // ---- MFMA ----
            const int row = lane & 15;
            const int d0  = (lane >> 4) * 8;
            const int sw  = (row & 7) << 3;
            const bf16x8 a0 = *reinterpret_cast<const bf16x8*>(&P[w][row * 64 + ((d0)      ^ sw)]);
            const bf16x8 a1 = *reinterpret_cast<const bf16x8*>(&P[w][row * 64 + ((d0 + 32) ^ sw)]);

            f32x4 acc0 = {0.f, 0.f, 0.f, 0.f}, acc1 = acc0, acc2 = acc0, acc3 = acc0;
            MFMA8(a0, a1)

            // ---- relu + C-fragments -> fp32 staging rows ----
            const int rb4 = (lane >> 4) * 4;
            const int cl  = lane & 15;
#pragma unroll
            for (int r = 0; r < 4; ++r) {
                M[w][(rb4 + r) * MST + cl + 0]  = fmaxf(acc0[r], 0.f);
                M[w][(rb4 + r) * MST + cl + 16] = fmaxf(acc1[r], 0.f);
                M[w][(rb4 + r) * MST + cl + 32] = fmaxf(acc2[r], 0.f);
                M[w][(rb4 + r) * MST + cl + 48] = fmaxf(acc3[r], 0.f);
            }

            // ---- accumulate rows into bin accumulator (lane=col: race-free) ----
            for (int r = 0; r < ctile; ++r) {
                const int acL = __builtin_amdgcn_readlane((int)tq.z, r) & 15;
                A[w][acL * 64 + lane] += M[w][r * MST + lane];
            }
        }

        // ---- flush bin: plain coalesced bf16 stores (covers zero-degree edges too) ----
        const int ebase = bin << 4;
#pragma unroll
        for (int r = 0; r < 16; ++r) {
            const int e = ebase + r;
            if (e < E_) aggbf[(size_t)e * DD + lane] = f2bf(A[w][r * 64 + lane]);
        }
    }
}

// ---------- update pass ----------
__global__ __launch_bounds__(256) void upd_fast(
    const unsigned short* __restrict__ xtab, const unsigned short* __restrict__ aggbf,
    const float* __restrict__ Wupd, float* __restrict__ out, int E_) {
    __shared__ unsigned short P[4][16 * 64];
    __shared__ float U[4][16 * MST];

    const int lane = threadIdx.x & 63;
    const int w    = threadIdx.x >> 6;

    bf16x8 bw[4][2];
    load_w_frags(Wupd, lane, bw);

    const int wave   = (blockIdx.x * blockDim.x + threadIdx.x) >> 6;
    const int nwaves = (gridDim.x * blockDim.x) >> 6;
    const int groups = E_ >> 4;

    for (int g = wave; g < groups; g += nwaves) {
        const int bu = g << 4;

#pragma unroll
        for (int half = 0; half < 2; ++half) {
            const int flat = half * 512 + lane * 8;
            const int row  = flat >> 6;
            const int colb = flat & 63;
            const uint4 v = *reinterpret_cast<const uint4*>(&aggbf[(size_t)bu * DD + flat]);
            *reinterpret_cast<uint4*>(&P[w][row * 64 + (colb ^ ((row & 7) << 3))]) = v;
        }

        const int row = lane & 15;
        const int d0  = (lane >> 4) * 8;
        const int sw  = (row & 7) << 3;
        const bf16x8 a0 = *reinterpret_cast<const bf16x8*>(&P[w][row * 64 + ((d0)      ^ sw)]);
        const bf16x8 a1 = *reinterpret_cast<const bf16x8*>(&P[w][row * 64 + ((d0 + 32) ^ sw)]);

        f32x4 acc0 = {0.f, 0.f, 0.f, 0.f}, acc1 = acc0, acc2 = acc0, acc3 = acc0;
        MFMA8(a0, a1)

        const int rb4 = (lane >> 4) * 4;
        const int cl  = lane & 15;
#pragma unroll
        for (int r = 0; r < 4; ++r) {
            U[w][(rb4 + r) * MST + cl + 0]  = acc0[r];
            U[w][(rb4 + r) * MST + cl + 16] = acc1[r];
            U[w][(rb4 + r) * MST + cl + 32] = acc2[r];
            U[w][(rb4 + r) * MST + cl + 48] = acc3[r];
        }

#pragma unroll
        for (int tt = 0; tt < 16; ++tt) {
            const int e   = bu + tt;
            const float x = bf2f(xtab[(size_t)e * DD + lane]);
            out[(size_t)e * DD + lane] = fmaxf(x + U[w][tt * MST + lane], 0.f);
        }
    }
}

// ---------- tier 1: fully general fallback ----------
__global__ __launch_bounds__(256) void tri_fb(
    const float* __restrict__ feat, const float* __restrict__ emb,
    const float* __restrict__ Wmsg, const int* __restrict__ rel,
    const int* __restrict__ ab, const int* __restrict__ bc,
    const int* __restrict__ ac, float* __restrict__ agg, int T_) {
    __shared__ unsigned short P[4][16 * 64];
    const int lane = threadIdx.x & 63;
    const int w    = threadIdx.x >> 6;
    bf16x8 bw[4][2];
    load_w_frags(Wmsg, lane, bw);
    const int wave   = (blockIdx.x * blockDim.x + threadIdx.x) >> 6;
    const int nwaves = (gridDim.x * blockDim.x) >> 6;
    const int groups = (T_ + 15) >> 4;
    for (int g = wave; g < groups; g += nwaves) {
        const int bu = __builtin_amdgcn_readfirstlane(g << 4);
#pragma unroll 4
        for (int tt = 0; tt < 16; ++tt) {
            const int t = bu + tt;
            float p = 0.f;
            if (t < T_) {
                const int ea = ab[t], eb = bc[t];
                const float xa = feat[ea * DD + lane] + emb[rel[ea] * DD + lane];
                const float xb = feat[eb * DD + lane] + emb[rel[eb] * DD + lane];
                p = xa * xb;
            }
            P[w][tt * 64 + (lane ^ ((tt & 7) << 3))] = f2bf(p);
        }
        const int row = lane & 15;
        const int d0  = (lane >> 4) * 8;
        const int sw  = (row & 7) << 3;
        const bf16x8 a0 = *reinterpret_cast<const bf16x8*>(&P[w][row * 64 + ((d0)      ^ sw)]);
        const bf16x8 a1 = *reinterpret_cast<const bf16x8*>(&P[w][row * 64 + ((d0 + 32) ^ sw)]);
        f32x4 acc0 = {0.f, 0.f, 0.f, 0.f}, acc1 = acc0, acc2 = acc0, acc3 = acc0;
        MFMA8(a0, a1)
        const int rb4 = (lane >> 4) * 4;
        const int cl  = lane & 15;
#pragma unroll
        for (int r = 0; r < 4; ++r) {
            const int t = bu + rb4 + r;
            if (t < T_) {
                float* dst = &agg[(size_t)ac[t] * DD + cl];
                atomicAdd(dst + 0,  fmaxf(acc0[r], 0.f));
                atomicAdd(dst + 16, fmaxf(acc1[r], 0.f));
                atomicAdd(dst + 32, fmaxf(acc2[r], 0.f));
                atomicAdd(dst + 48, fmaxf(acc3[r], 0.f));
            }
        }
    }
}

__global__ __launch_bounds__(256) void upd_fb(
    const float* __restrict__ feat, const float* __restrict__ emb,
    const float* __restrict__ Wupd, const int* __restrict__ rel,
    float* __restrict__ agg_out, int E_) {
    __shared__ unsigned short P[4][16 * 64];
    __shared__ float U[4][16 * MST];
    const int lane = threadIdx.x & 63;
    const int w    = threadIdx.x >> 6;
    bf16x8 bw[4][2];
    load_w_frags(Wupd, lane, bw);
    const int wave   = (blockIdx.x * blockDim.x + threadIdx.x) >> 6;
    const int nwaves = (gridDim.x * blockDim.x) >> 6;
    const int groups = (E_ + 15) >> 4;
    for (int g = wave; g < groups; g += nwaves) {
        const int bu = __builtin_amdgcn_readfirstlane(g << 4);
#pragma unroll 4
        for (int tt = 0; tt < 16; ++tt) {
            const int e = bu + tt;
            const float v = (e < E_) ? agg_out[(size_t)e * DD + lane] : 0.f;
            P[w][tt * 64 + (lane ^ ((tt & 7) << 3))] = f2bf(v);
        }
        const int row = lane & 15;
        const int d0  = (lane >> 4) * 8;
        const int sw  = (row & 7) << 3;
        const bf16x8 a0 = *reinterpret_cast<const bf16x8*>(&P[w][row * 64 + ((d0)      ^ sw)]);
        const bf16x8 a1 = *reinterpret_cast<const bf16x8*>(&P[w][row * 64 + ((d0 + 32) ^ sw)]);
        f32x4 acc0 = {0.f, 0.f, 0.f, 0.f}, acc1 = acc0, acc2 = acc0, acc3 = acc0;
        MFMA8(a0, a1)
        const int rb4 = (lane >> 4) * 4;
        const int cl  = lane & 15;
#pragma unroll
        for (int r = 0; r < 4; ++r) {
            U[w][(rb4 + r) * MST + cl + 0]  = acc0[r];
            U[w][(rb4 + r) * MST + cl + 16] = acc1[r];
            U[w][(rb4 + r) * MST + cl + 32] = acc2[r];
            U[w][(rb4 + r) * MST + cl + 48] = acc3[r];
        }
#pragma unroll 4
        for (int tt = 0; tt < 16; ++tt) {
            const int e = bu + tt;
            if (e < E_) {
                const float x = feat[(size_t)e * DD + lane] + emb[rel[e] * DD + lane];
                agg_out[(size_t)e * DD + lane] = fmaxf(x + U[w][tt * MST + lane], 0.f);
            }
        }
    }
}

extern "C" void kernel_launch(void* const* d_in, const int* in_sizes, int n_in,
                              void* d_out, int out_size, void* d_ws, size_t ws_size,
                              hipStream_t stream) {
    const float* feat = (const float*)d_in[0];
    const float* emb  = (const float*)d_in[1];
    const float* Wmsg = (const float*)d_in[2];
    const float* Wupd = (const float*)d_in[3];
    const int*   rel  = (const int*)d_in[4];
    const int*   ab   = (const int*)d_in[5];
    const int*   bc   = (const int*)d_in[6];
    const int*   ac   = (const int*)d_in[7];

    const int E_ = in_sizes[0] / DD;
    const int T_ = in_sizes[5];

    const int    NBINS    = (E_ + 15) >> 4;
    const size_t xbytes   = (size_t)E_ * DD * sizeof(unsigned short);   // 128 MB
    const size_t tepbytes = (size_t)T_ * sizeof(uint4);                 // 32 MB
    const size_t cbytes   = ((size_t)NBINS * sizeof(unsigned int) + 255u) & ~(size_t)255u;
    const int    nblk     = (NBINS + SCAN_CH - 1) / SCAN_CH;
    const size_t needB    = 2 * xbytes + tepbytes + 2 * cbytes + 4096 * sizeof(unsigned int);

    const bool fastB = ((E_ & 15) == 0) && (nblk <= 1024) && (ws_size >= needB);

    if (fastB) {
        char* p = (char*)d_ws;
        unsigned short* xtab  = (unsigned short*)p;  p += xbytes;
        unsigned short* aggbf = (unsigned short*)p;  p += xbytes;
        uint4*          tep   = (uint4*)p;           p += tepbytes;
        unsigned int*   cnt   = (unsigned int*)p;    p += cbytes;
        unsigned int*   offs  = (unsigned int*)p;    p += cbytes;
        unsigned int*   bsum  = (unsigned int*)p;

        hipMemsetAsync(cnt, 0, (size_t)NBINS * sizeof(unsigned int), stream);
        hipLaunchKernelGGL(xprep_kernel, dim3(2048), dim3(256), 0, stream,
                           (const float4*)feat, (const float4*)emb, rel, xtab, E_ * 16);
        hipLaunchKernelGGL(hist_bin_kernel, dim3(2048), dim3(256), 0, stream, ac, cnt, T_);
        hipLaunchKernelGGL(scanA_kernel, dim3(nblk), dim3(256), 0, stream, cnt, bsum, NBINS);
        hipLaunchKernelGGL(scanB_kernel, dim3(1), dim3(1024), 0, stream, bsum, nblk);
        hipLaunchKernelGGL(scanC_kernel, dim3(nblk), dim3(256), 0, stream, cnt, bsum, offs, NBINS);
        hipLaunchKernelGGL(scatter_pre_kernel, dim3(2048), dim3(256), 0, stream,
                           ab, bc, ac, offs, tep, T_);
        hipLaunchKernelGGL(tri_bin_kernel, dim3(2048), dim3(256), 0, stream,
                           xtab, Wmsg, tep, cnt, offs, aggbf, E_, NBINS);
        hipLaunchKernelGGL(upd_fast, dim3(2048), dim3(256), 0, stream,
                           xtab, aggbf, Wupd, (float*)d_out, E_);
    } else {
        float* agg = (float*)d_out;
        hipMemsetAsync(d_out, 0, (size_t)E_ * DD * sizeof(float), stream);
        hipLaunchKernelGGL(tri_fb, dim3(2048), dim3(256), 0, stream,
                           feat, emb, Wmsg, rel, ab, bc, ac, agg, T_);
        hipLaunchKernelGGL(upd_fb, dim3(2048), dim3(256), 0, stream,
                           feat, emb, Wupd, rel, agg, E_);
    }
}

// Round 10
// 563.083 us; speedup vs baseline: 1.2649x; 1.2649x over previous
//
#include <hip/hip_runtime.h>
#include <hip/hip_bf16.h>

#define DD 64
#define SCAN_CH 1024
#define MST 68   // fp32 LDS row stride

typedef __attribute__((ext_vector_type(8))) short bf16x8;
typedef __attribute__((ext_vector_type(4))) float f32x4;

__device__ __forceinline__ unsigned short f2bf(float f) {
    unsigned int u = __float_as_uint(f);
    unsigned int r = (u + 0x7fffu + ((u >> 16) & 1u)) >> 16;   // RNE
    return (unsigned short)r;
}
__device__ __forceinline__ float bf2f(unsigned short u) {
    return __uint_as_float((unsigned int)u << 16);
}
__device__ __forceinline__ unsigned int pack2(float lo, float hi) {
    return (unsigned int)f2bf(lo) | ((unsigned int)f2bf(hi) << 16);
}
// single-instruction packed fp32->bf16x2 (RNE)
__device__ __forceinline__ unsigned int cvt_pk_bf16(float lo, float hi) {
    unsigned int r;
    asm("v_cvt_pk_bf16_f32 %0, %1, %2" : "=v"(r) : "v"(lo), "v"(hi));
    return r;
}
// product of two bf16x2 dwords -> bf16x2 dword (3 unpack-ops + 2 mul + 1 cvt_pk)
__device__ __forceinline__ unsigned int prod2(unsigned int a, unsigned int b) {
    const float la = __uint_as_float(a << 16);
    const float ha = __uint_as_float(a & 0xffff0000u);
    const float lb = __uint_as_float(b << 16);
    const float hb = __uint_as_float(b & 0xffff0000u);
    return cvt_pk_bf16(la * lb, ha * hb);
}
__device__ __forceinline__ void pk_atomic_add_bf16(unsigned short* addr, unsigned int data) {
    asm volatile("global_atomic_pk_add_bf16 %0, %1, off" :: "v"(addr), "v"(data) : "memory");
}

// B frag for 16x16x32: lane l holds B[k = ks*32 + (l>>4)*8 + b][col = nt*16 + (l&15)]
__device__ __forceinline__ void load_w_frags(const float* __restrict__ W, int lane,
                                             bf16x8 bw[4][2]) {
    const int kl = (lane >> 4) * 8;
    const int cl = lane & 15;
#pragma unroll
    for (int nt = 0; nt < 4; ++nt)
#pragma unroll
        for (int ks = 0; ks < 2; ++ks)
#pragma unroll
            for (int b = 0; b < 8; ++b)
                bw[nt][ks][b] = (short)f2bf(W[(ks * 32 + kl + b) * DD + nt * 16 + cl]);
}

#define MFMA8(A0, A1)                                                          \
    acc0 = __builtin_amdgcn_mfma_f32_16x16x32_bf16(A0, bw[0][0], acc0, 0, 0, 0); \
    acc0 = __builtin_amdgcn_mfma_f32_16x16x32_bf16(A1, bw[0][1], acc0, 0, 0, 0); \
    acc1 = __builtin_amdgcn_mfma_f32_16x16x32_bf16(A0, bw[1][0], acc1, 0, 0, 0); \
    acc1 = __builtin_amdgcn_mfma_f32_16x16x32_bf16(A1, bw[1][1], acc1, 0, 0, 0); \
    acc2 = __builtin_amdgcn_mfma_f32_16x16x32_bf16(A0, bw[2][0], acc2, 0, 0, 0); \
    acc2 = __builtin_amdgcn_mfma_f32_16x16x32_bf16(A1, bw[2][1], acc2, 0, 0, 0); \
    acc3 = __builtin_amdgcn_mfma_f32_16x16x32_bf16(A0, bw[3][0], acc3, 0, 0, 0); \
    acc3 = __builtin_amdgcn_mfma_f32_16x16x32_bf16(A1, bw[3][1], acc3, 0, 0, 0);

// ---------- x-table prep + fused ac histogram ----------
__global__ __launch_bounds__(256) void xprep_hist_kernel(
    const float4* __restrict__ feat4, const float4* __restrict__ emb4,
    const int* __restrict__ rel, unsigned short* __restrict__ xtab, int n4,
    const int* __restrict__ ac, unsigned int* __restrict__ cnt, int T_) {
    const int tid0   = blockIdx.x * blockDim.x + threadIdx.x;
    const int stride = gridDim.x * blockDim.x;
    for (int t = tid0; t < T_; t += stride) atomicAdd(&cnt[ac[t]], 1u);   // fire-and-forget
    for (int i = tid0; i < n4; i += stride) {
        const int e  = i >> 4;
        const int re = rel[e];
        const float4 f = feat4[i];
        const float4 g = emb4[re * 16 + (i & 15)];
        ushort4 o;
        o.x = f2bf(f.x + g.x); o.y = f2bf(f.y + g.y);
        o.z = f2bf(f.z + g.z); o.w = f2bf(f.w + g.w);
        *reinterpret_cast<ushort4*>(&xtab[(size_t)i * 4]) = o;
    }
}

// ---------- scan (edge-level, n = E) ----------
__global__ __launch_bounds__(256) void scanA_kernel(const unsigned int* __restrict__ cnt,
                                                    unsigned int* __restrict__ bsum, int n) {
    __shared__ unsigned int s[256];
    const int b = blockIdx.x, tid = threadIdx.x;
    const int base = b * SCAN_CH + tid * 4;
    unsigned int v = 0;
#pragma unroll
    for (int k = 0; k < 4; ++k) { const int i = base + k; if (i < n) v += cnt[i]; }
    s[tid] = v; __syncthreads();
    for (int off = 128; off > 0; off >>= 1) {
        if (tid < off) s[tid] += s[tid + off];
        __syncthreads();
    }
    if (tid == 0) bsum[b] = s[0];
}

__global__ __launch_bounds__(1024) void scanB_kernel(unsigned int* bsum, int nb) {
    __shared__ unsigned int s[1024];
    const int tid = threadIdx.x;
    s[tid] = (tid < nb) ? bsum[tid] : 0u;
    __syncthreads();
    for (int off = 1; off < 1024; off <<= 1) {
        const unsigned int t = (tid >= off) ? s[tid - off] : 0u;
        __syncthreads();
        s[tid] += t;
        __syncthreads();
    }
    if (tid < nb) bsum[tid] = (tid == 0) ? 0u : s[tid - 1];   // exclusive
}

// scanC: writes offs AND zero-fills aggbf rows that will only receive atomic
// contributions: deg==0 edges, and edges whose position range [lo,hi] touches a
// wave boundary (multiple of S, or T at the very end).
__global__ __launch_bounds__(256) void scanC_kernel(
    const unsigned int* __restrict__ cnt, const unsigned int* __restrict__ bsum,
    unsigned int* __restrict__ offs, unsigned short* __restrict__ aggbf,
    int n, int S, int Ttot) {
    __shared__ unsigned int s[256];
    const int b = blockIdx.x, tid = threadIdx.x;
    const int base = b * SCAN_CH + tid * 4;
    unsigned int v[4], sum = 0;
#pragma unroll
    for (int k = 0; k < 4; ++k) { const int i = base + k; v[k] = (i < n) ? cnt[i] : 0u; sum += v[k]; }
    s[tid] = sum; __syncthreads();
    for (int off = 1; off < 256; off <<= 1) {
        const unsigned int t = (tid >= off) ? s[tid - off] : 0u;
        __syncthreads();
        s[tid] += t;
        __syncthreads();
    }
    unsigned int run = bsum[b] + (s[tid] - sum);
#pragma unroll
    for (int k = 0; k < 4; ++k) {
        const int i = base + k;
        if (i < n) {
            offs[i] = run;
            const int lo = (int)run;
            const int hi = (int)(run + v[k]);
            const int fl = (lo == 0) ? -1 : (lo - 1) / S;
            const bool needZero = (v[k] == 0u) || (hi >= Ttot) || (hi / S > fl);
            if (needZero) {
                const uint4 z = make_uint4(0u, 0u, 0u, 0u);
                unsigned short* row = &aggbf[(size_t)i * DD];
#pragma unroll
                for (int j = 0; j < 8; ++j)
                    *reinterpret_cast<uint4*>(&row[j * 8]) = z;
            }
        }
        run += v[k];
    }
}

// tep[pos] = {ab,bc,ac,0} (pre-dereferenced; tri reads tep linearly)
__global__ __launch_bounds__(256) void scatter_pre_kernel(
    const int* __restrict__ ab, const int* __restrict__ bc, const int* __restrict__ ac,
    unsigned int* __restrict__ offs, uint4* __restrict__ tep, int T_) {
    int t = blockIdx.x * blockDim.x + threadIdx.x;
    const int stride = gridDim.x * blockDim.x;
    for (; t < T_; t += stride) {
        const int e = ac[t];
        const unsigned int pos = atomicAdd(&offs[e], 1u);
        tep[pos] = make_uint4((unsigned)ab[t], (unsigned)bc[t], (unsigned)e, 0u);
    }
}

// ---------- fused CSR message+reduce, lean-VALU gather ----------
__global__ __launch_bounds__(256) void tri_csr3_kernel(
    const unsigned short* __restrict__ xtab, const float* __restrict__ Wmsg,
    const uint4* __restrict__ tep, unsigned short* __restrict__ aggbf,
    int T_, int S) {
    __shared__ unsigned short P[4][16 * 64];
    __shared__ float M[4][16 * MST];

    const int lane = threadIdx.x & 63;
    const int w    = threadIdx.x >> 6;

    bf16x8 bw[4][2];
    load_w_frags(Wmsg, lane, bw);

    const int gw = (blockIdx.x * blockDim.x + threadIdx.x) >> 6;
    const int p0 = gw * S;
    if (p0 >= T_) return;
    const int p1 = min(p0 + S, T_);

    const int rh = lane >> 3;          // row within half (0..7)
    const int cb = (lane & 7) * 8;     // 8-elem chunk within row

    int cur_e = -1; float sum = 0.f;
    int e_sv  = -1; float sum_sv = 0.f;
    bool have_sv = false;

    for (int t0 = p0; t0 < p1; t0 += 16) {
        const int cnt = min(16, p1 - t0);
        const uint4 tq = tep[t0 + min(lane & 15, cnt - 1)];

        // ---- gathers: every lane loads its own a-chunk + b-chunk (no data shfl) ----
#pragma unroll
        for (int half = 0; half < 2; ++half) {
            const int ttl = half * 8 + rh;
            const int eA  = __shfl((int)tq.x, ttl, 64);
            const int eB  = __shfl((int)tq.y, ttl, 64);
            const uint4 va = *reinterpret_cast<const uint4*>(&xtab[(size_t)eA * DD + cb]);
            const uint4 vb = *reinterpret_cast<const uint4*>(&xtab[(size_t)eB * DD + cb]);
            uint4 pk;
            pk.x = prod2(va.x, vb.x);
            pk.y = prod2(va.y, vb.y);
            pk.z = prod2(va.z, vb.z);
            pk.w = prod2(va.w, vb.w);
            const int swz = (ttl & 7) << 3;
            *reinterpret_cast<uint4*>(&P[w][ttl * 64 + (cb ^ swz)]) = pk;
        }

        // ---- MFMA ----
        const int row = lane & 15;
        const int d0  = (lane >> 4) * 8;
        const int sw  = (row & 7) << 3;
        const bf16x8 a0 = *reinterpret_cast<const bf16x8*>(&P[w][row * 64 + ((d0)      ^ sw)]);
        const bf16x8 a1 = *reinterpret_cast<const bf16x8*>(&P[w][row * 64 + ((d0 + 32) ^ sw)]);

        f32x4 acc0 = {0.f, 0.f, 0.f, 0.f}, acc1 = acc0, acc2 = acc0, acc3 = acc0;
        MFMA8(a0, a1)

        // ---- relu + C-fragments -> fp32 LDS rows ----
        const int rb4 = (lane >> 4) * 4;
        const int cl  = lane & 15;
#pragma unroll
        for (int r = 0; r < 4; ++r) {
            M[w][(rb4 + r) * MST + cl + 0]  = fmaxf(acc0[r], 0.f);
            M[w][(rb4 + r) * MST + cl + 16] = fmaxf(acc1[r], 0.f);
            M[w][(rb4 + r) * MST + cl + 32] = fmaxf(acc2[r], 0.f);
            M[w][(rb4 + r) * MST + cl + 48] = fmaxf(acc3[r], 0.f);
        }

        // ---- run-length reduce (sorted => equal-e rows adjacent) ----
        for (int r = 0; r < cnt; ++r) {
            const int e_r = __builtin_amdgcn_readlane((int)tq.z, r);
            if (e_r != cur_e) {
                if (cur_e >= 0) {
                    if (!have_sv) { e_sv = cur_e; sum_sv = sum; have_sv = true; }
                    else aggbf[(size_t)cur_e * DD + lane] = f2bf(sum);  // exclusive owner
                }
                cur_e = e_r; sum = 0.f;
            }
            sum += M[w][r * MST + lane];
        }
    }

    // ---- boundary edges: pk-atomic (rows pre-zeroed by scanC) ----
    {
        const float nsum = __shfl_xor(sum, 1, 64);
        if (cur_e >= 0 && !(lane & 1))
            pk_atomic_add_bf16(&aggbf[(size_t)cur_e * DD + lane], pack2(sum, nsum));
        if (have_sv) {
            const float nsv = __shfl_xor(sum_sv, 1, 64);
            if (!(lane & 1))
                pk_atomic_add_bf16(&aggbf[(size_t)e_sv * DD + lane], pack2(sum_sv, nsv));
        }
    }
}

// ---------- update pass ----------
__global__ __launch_bounds__(256) void upd_fast(
    const unsigned short* __restrict__ xtab, const unsigned short* __restrict__ aggbf,
    const float* __restrict__ Wupd, float* __restrict__ out, int E_) {
    __shared__ unsigned short P[4][16 * 64];
    __shared__ float U[4][16 * MST];

    const int lane = threadIdx.x & 63;
    const int w    = threadIdx.x >> 6;

    bf16x8 bw[4][2];
    load_w_frags(Wupd, lane, bw);

    const int wave   = (blockIdx.x * blockDim.x + threadIdx.x) >> 6;
    const int nwaves = (gridDim.x * blockDim.x) >> 6;
    const int groups = E_ >> 4;

    for (int g = wave; g < groups; g += nwaves) {
        const int bu = g << 4;

#pragma unroll
        for (int half = 0; half < 2; ++half) {
            const int flat = half * 512 + lane * 8;
            const int row  = flat >> 6;
            const int colb = flat & 63;
            const uint4 v = *reinterpret_cast<const uint4*>(&aggbf[(size_t)bu * DD + flat]);
            *reinterpret_cast<uint4*>(&P[w][row * 64 + (colb ^ ((row & 7) << 3))]) = v;
        }

        const int row = lane & 15;
        const int d0  = (lane >> 4) * 8;
        const int sw  = (row & 7) << 3;
        const bf16x8 a0 = *reinterpret_cast<const bf16x8*>(&P[w][row * 64 + ((d0)      ^ sw)]);
        const bf16x8 a1 = *reinterpret_cast<const bf16x8*>(&P[w][row * 64 + ((d0 + 32) ^ sw)]);

        f32x4 acc0 = {0.f, 0.f, 0.f, 0.f}, acc1 = acc0, acc2 = acc0, acc3 = acc0;
        MFMA8(a0, a1)

        const int rb4 = (lane >> 4) * 4;
        const int cl  = lane & 15;
#pragma unroll
        for (int r = 0; r < 4; ++r) {
            U[w][(rb4 + r) * MST + cl + 0]  = acc0[r];
            U[w][(rb4 + r) * MST + cl + 16] = acc1[r];
            U[w][(rb4 + r) * MST + cl + 32] = acc2[r];
            U[w][(rb4 + r) * MST + cl + 48] = acc3[r];
        }

#pragma unroll
        for (int tt = 0; tt < 16; ++tt) {
            const int e   = bu + tt;
            const float x = bf2f(xtab[(size_t)e * DD + lane]);
            out[(size_t)e * DD + lane] = fmaxf(x + U[w][tt * MST + lane], 0.f);
        }
    }
}

// ---------- tier 1: fully general fallback ----------
__global__ __launch_bounds__(256) void tri_fb(
    const float* __restrict__ feat, const float* __restrict__ emb,
    const float* __restrict__ Wmsg, const int* __restrict__ rel,
    const int* __restrict__ ab, const int* __restrict__ bc,
    const int* __restrict__ ac, float* __restrict__ agg, int T_) {
    __shared__ unsigned short P[4][16 * 64];
    const int lane = threadIdx.x & 63;
    const int w    = threadIdx.x >> 6;
    bf16x8 bw[4][2];
    load_w_frags(Wmsg, lane, bw);
    const int wave   = (blockIdx.x * blockDim.x + threadIdx.x) >> 6;
    const int nwaves = (gridDim.x * blockDim.x) >> 6;
    const int groups = (T_ + 15) >> 4;
    for (int g = wave; g < groups; g += nwaves) {
        const int bu = __builtin_amdgcn_readfirstlane(g << 4);
#pragma unroll 4
        for (int tt = 0; tt < 16; ++tt) {
            const int t = bu + tt;
            float p = 0.f;
            if (t < T_) {
                const int ea = ab[t], eb = bc[t];
                const float xa = feat[ea * DD + lane] + emb[rel[ea] * DD + lane];
                const float xb = feat[eb * DD + lane] + emb[rel[eb] * DD + lane];
                p = xa * xb;
            }
            P[w][tt * 64 + (lane ^ ((tt & 7) << 3))] = f2bf(p);
        }
        const int row = lane & 15;
        const int d0  = (lane >> 4) * 8;
        const int sw  = (row & 7) << 3;
        const bf16x8 a0 = *reinterpret_cast<const bf16x8*>(&P[w][row * 64 + ((d0)      ^ sw)]);
        const bf16x8 a1 = *reinterpret_cast<const bf16x8*>(&P[w][row * 64 + ((d0 + 32) ^ sw)]);
        f32x4 acc0 = {0.f, 0.f, 0.f, 0.f}, acc1 = acc0, acc2 = acc0, acc3 = acc0;
        MFMA8(a0, a1)
        const int rb4 = (lane >> 4) * 4;
        const int cl  = lane & 15;
#pragma unroll
        for (int r = 0; r < 4; ++r) {
            const int t = bu + rb4 + r;
            if (t < T_) {
                float* dst = &agg[(size_t)ac[t] * DD + cl];
                atomicAdd(dst + 0,  fmaxf(acc0[r], 0.f));
                atomicAdd(dst + 16, fmaxf(acc1[r], 0.f));
                atomicAdd(dst + 32, fmaxf(acc2[r], 0.f));
                atomicAdd(dst + 48, fmaxf(acc3[r], 0.f));
            }
        }
    }
}

__global__ __launch_bounds__(256) void upd_fb(
    const float* __restrict__ feat, const float* __restrict__ emb,
    const float* __restrict__ Wupd, const int* __restrict__ rel,
    float* __restrict__ agg_out, int E_) {
    __shared__ unsigned short P[4][16 * 64];
    __shared__ float U[4][16 * MST];
    const int lane = threadIdx.x & 63;
    const int w    = threadIdx.x >> 6;
    bf16x8 bw[4][2];
    load_w_frags(Wupd, lane, bw);
    const int wave   = (blockIdx.x * blockDim.x + threadIdx.x) >> 6;
    const int nwaves = (gridDim.x * blockDim.x) >> 6;
    const int groups = (E_ + 15) >> 4;
    for (int g = wave; g < groups; g += nwaves) {
        const int bu = __builtin_amdgcn_readfirstlane(g << 4);
#pragma unroll 4
        for (int tt = 0; tt < 16; ++tt) {
            const int e = bu + tt;
            const float v = (e < E_) ? agg_out[(size_t)e * DD + lane] : 0.f;
            P[w][tt * 64 + (lane ^ ((tt & 7) << 3))] = f2bf(v);
        }
        const int row = lane & 15;
        const int d0  = (lane >> 4) * 8;
        const int sw  = (row & 7) << 3;
        const bf16x8 a0 = *reinterpret_cast<const bf16x8*>(&P[w][row * 64 + ((d0)      ^ sw)]);
        const bf16x8 a1 = *reinterpret_cast<const bf16x8*>(&P[w][row * 64 + ((d0 + 32) ^ sw)]);
        f32x4 acc0 = {0.f, 0.f, 0.f, 0.f}, acc1 = acc0, acc2 = acc0, acc3 = acc0;
        MFMA8(a0, a1)
        const int rb4 = (lane >> 4) * 4;
        const int cl  = lane & 15;
#pragma unroll
        for (int r = 0; r < 4; ++r) {
            U[w][(rb4 + r) * MST + cl + 0]  = acc0[r];
            U[w][(rb4 + r) * MST + cl + 16] = acc1[r];
            U[w][(rb4 + r) * MST + cl + 32] = acc2[r];
            U[w][(rb4 + r) * MST + cl + 48] = acc3[r];
        }
#pragma unroll 4
        for (int tt = 0; tt < 16; ++tt) {
            const int e = bu + tt;
            if (e < E_) {
                const float x = feat[(size_t)e * DD + lane] + emb[rel[e] * DD + lane];
                agg_out[(size_t)e * DD + lane] = fmaxf(x + U[w][tt * MST + lane], 0.f);
            }
        }
    }
}

extern "C" void kernel_launch(void* const* d_in, const int* in_sizes, int n_in,
                              void* d_out, int out_size, void* d_ws, size_t ws_size,
                              hipStream_t stream) {
    const float* feat = (const float*)d_in[0];
    const float* emb  = (const float*)d_in[1];
    const float* Wmsg = (const float*)d_in[2];
    const float* Wupd = (const float*)d_in[3];
    const int*   rel  = (const int*)d_in[4];
    const int*   ab   = (const int*)d_in[5];
    const int*   bc   = (const int*)d_in[6];
    const int*   ac   = (const int*)d_in[7];

    const int E_ = in_sizes[0] / DD;
    const int T_ = in_sizes[5];

    const size_t xbytes   = (size_t)E_ * DD * sizeof(unsigned short);   // 128 MB
    const size_t tepbytes = (size_t)T_ * sizeof(uint4);                 // 32 MB
    const size_t cbytes   = ((size_t)E_ * sizeof(unsigned int) + 255u) & ~(size_t)255u;
    const int    nblk     = (E_ + SCAN_CH - 1) / SCAN_CH;
    const size_t needC    = 2 * xbytes + tepbytes + 2 * cbytes + 4096 * sizeof(unsigned int);

    const bool fastC = ((E_ & 15) == 0) && (nblk <= 1024) && (ws_size >= needC);

    if (fastC) {
        char* p = (char*)d_ws;
        unsigned short* xtab  = (unsigned short*)p;  p += xbytes;
        unsigned short* aggbf = (unsigned short*)p;  p += xbytes;
        uint4*          tep   = (uint4*)p;           p += tepbytes;
        unsigned int*   cnt   = (unsigned int*)p;    p += cbytes;
        unsigned int*   offs  = (unsigned int*)p;    p += cbytes;
        unsigned int*   bsum  = (unsigned int*)p;

        const int nwaves = 2048 * 256 / 64;                       // 8192 waves
        int S = (T_ + nwaves - 1) / nwaves;
        S = (S + 15) & ~15;                                       // multiple of 16

        hipMemsetAsync(cnt, 0, (size_t)E_ * sizeof(unsigned int), stream);
        hipLaunchKernelGGL(xprep_hist_kernel, dim3(2048), dim3(256), 0, stream,
                           (const float4*)feat, (const float4*)emb, rel, xtab, E_ * 16,
                           ac, cnt, T_);
        hipLaunchKernelGGL(scanA_kernel, dim3(nblk), dim3(256), 0, stream, cnt, bsum, E_);
        hipLaunchKernelGGL(scanB_kernel, dim3(1), dim3(1024), 0, stream, bsum, nblk);
        hipLaunchKernelGGL(scanC_kernel, dim3(nblk), dim3(256), 0, stream,
                           cnt, bsum, offs, aggbf, E_, S, T_);
        hipLaunchKernelGGL(scatter_pre_kernel, dim3(2048), dim3(256), 0, stream,
                           ab, bc, ac, offs, tep, T_);
        hipLaunchKernelGGL(tri_csr3_kernel, dim3(2048), dim3(256), 0, stream,
                           xtab, Wmsg, tep, aggbf, T_, S);
        hipLaunchKernelGGL(upd_fast, dim3(2048), dim3(256), 0, stream,
                           xtab, aggbf, Wupd, (float*)d_out, E_);
    } else {
        float* agg = (float*)d_out;
        hipMemsetAsync(d_out, 0, (size_t)E_ * DD * sizeof(float), stream);
        hipLaunchKernelGGL(tri_fb, dim3(2048), dim3(256), 0, stream,
                           feat, emb, Wmsg, rel, ab, bc, ac, agg, T_);
        hipLaunchKernelGGL(upd_fb, dim3(2048), dim3(256), 0, stream,
                           feat, emb, Wupd, rel, agg, E_);
    }
}